// Round 5
// baseline (240.808 us; speedup 1.0000x reference)
//
#include <hip/hip_runtime.h>

// LaneAttention: per-lane MLP score -> per-group(8) softmax -> weighted pool of
// concat(ht, info, future) into out[32768, 192] fp32.
//
// R5: the 2.3 TB/s plateau across R0/R2/R3 is per-CU line-request-queue bound:
// row-per-lane loads touch 64 distinct lines per instruction (64 lines x 64B /
// 900cy ~= 2.9 TB/s ceiling). Fix: coalesce phase 1 via an LDS transpose like
// R1, but with single-wave 64-thread blocks (16 KB LDS -> 10 blocks/CU) and NO
// s_barrier: DS ops are in-order within a wave, so explicit lgkmcnt fences
// suffice. Info loads are issued before the ht-MLP so they fly during compute.
// Phase 2 is float4-wide (16-line coalesced insts) with cross-quad shuffle
// reductions. Rotate swizzle (feat c of row r at word r*64+((c+r)&63)) keeps
// LDS conflict-free and W1 indices wave-uniform (scalar loads).

#define LGKM_FENCE() asm volatile("s_waitcnt lgkmcnt(0)" ::: "memory")

__global__ __launch_bounds__(64) void lane_attn_kernel(
    const float* __restrict__ ht,     // [M,64]
    const float* __restrict__ info,   // [M,64]
    const float* __restrict__ fut,    // [M,64]
    const float* __restrict__ W1,     // [128,16]
    const float* __restrict__ b1,     // [16]
    const float* __restrict__ W2,     // [16]
    const float* __restrict__ b2,     // [1]
    const int*   __restrict__ seg,    // [M]
    float*       __restrict__ out)    // [N_GROUPS,192]
{
    __shared__ float tile[64 * 64];   // 16 KB, rotate-swizzled

    const int t    = threadIdx.x;     // 0..63, one wave
    const int base = blockIdx.x * 64;

    const float4* ht4 = (const float4*)ht;
    const float4* in4 = (const float4*)info;
    const float4* fu4 = (const float4*)fut;
    const int fbase = base * 16;      // float4 index of this wave's tile

    // ---- issue ht loads: 16 coalesced dwordx4 (16 lines each) ----
    float4 hv[16];
#pragma unroll
    for (int it = 0; it < 16; ++it) hv[it] = ht4[fbase + it * 64 + t];

    // ---- stage ht into LDS (rotate swizzle) ----
#pragma unroll
    for (int it = 0; it < 16; ++it) {
        const int f  = it * 64 + t;
        const int r  = f >> 4;
        const int c0 = (f & 15) << 2;
        float* rb = &tile[r * 64];
        rb[(c0 + 0 + r) & 63] = hv[it].x;
        rb[(c0 + 1 + r) & 63] = hv[it].y;
        rb[(c0 + 2 + r) & 63] = hv[it].z;
        rb[(c0 + 3 + r) & 63] = hv[it].w;
    }

    // ---- issue info loads NOW so they are in flight during the ht-MLP ----
    float4 iv[16];
#pragma unroll
    for (int it = 0; it < 16; ++it) iv[it] = in4[fbase + it * 64 + t];

    LGKM_FENCE();   // ht tile visible to all lanes (in-order DS pipe, 1 wave)

    float h[16];
#pragma unroll
    for (int j = 0; j < 16; ++j) h[j] = b1[j];

    {
        const int rb = t * 64;
#pragma unroll 8
        for (int k = 0; k < 64; ++k) {
            const float x = tile[rb + ((k + t) & 63)];
#pragma unroll
            for (int j = 0; j < 16; ++j)
                h[j] = fmaf(x, W1[k * 16 + j], h[j]);
        }
    }

    LGKM_FENCE();   // all reads drained before overwrite

    // ---- stage info into LDS ----
#pragma unroll
    for (int it = 0; it < 16; ++it) {
        const int f  = it * 64 + t;
        const int r  = f >> 4;
        const int c0 = (f & 15) << 2;
        float* rb = &tile[r * 64];
        rb[(c0 + 0 + r) & 63] = iv[it].x;
        rb[(c0 + 1 + r) & 63] = iv[it].y;
        rb[(c0 + 2 + r) & 63] = iv[it].z;
        rb[(c0 + 3 + r) & 63] = iv[it].w;
    }

    LGKM_FENCE();

    {
        const int rb = t * 64;
#pragma unroll 8
        for (int k = 0; k < 64; ++k) {
            const float x = tile[rb + ((k + t) & 63)];
#pragma unroll
            for (int j = 0; j < 16; ++j)
                h[j] = fmaf(x, W1[(64 + k) * 16 + j], h[j]);
        }
    }

    float score = b2[0];
#pragma unroll
    for (int j = 0; j < 16; ++j)
        score = fmaf(fmaxf(h[j], 0.0f), W2[j], score);

    // ---- softmax within each 8-lane subgroup (lane t <-> row base+t) ----
    float m = score;
    m = fmaxf(m, __shfl_xor(m, 1));
    m = fmaxf(m, __shfl_xor(m, 2));
    m = fmaxf(m, __shfl_xor(m, 4));
    float e = __expf(score - m);
    float s = e;
    s += __shfl_xor(s, 1);
    s += __shfl_xor(s, 2);
    s += __shfl_xor(s, 4);
    const float prob = e / s;   // lane t holds prob of row base+t

    // ---- phase 2: float4-wide weighted pooling ----
    // lane: c4 = t&15 covers cols 4c4..4c4+3, q = t>>4 covers row r0+i2*4+q.
    // Each load inst: 4 rows x 256B contiguous = 16 lines. Partial sums are
    // reduced across q by shfl_xor(16,32); quad q stores array q.
    const int c4 = t & 15;
    const int q  = t >> 4;

#pragma unroll 2
    for (int gg = 0; gg < 8; ++gg) {
        const int r0  = base + gg * 8;
        const int gid = seg[r0];            // wave-uniform
        float4 aH = {0.f, 0.f, 0.f, 0.f};
        float4 aI = {0.f, 0.f, 0.f, 0.f};
        float4 aF = {0.f, 0.f, 0.f, 0.f};
#pragma unroll
        for (int i2 = 0; i2 < 2; ++i2) {
            const int row = r0 + i2 * 4 + q;
            const float p = __shfl(prob, gg * 8 + i2 * 4 + q);
            const float4 vh = ht4[row * 16 + c4];
            const float4 vi = in4[row * 16 + c4];
            const float4 vf = fu4[row * 16 + c4];
            aH.x = fmaf(p, vh.x, aH.x); aH.y = fmaf(p, vh.y, aH.y);
            aH.z = fmaf(p, vh.z, aH.z); aH.w = fmaf(p, vh.w, aH.w);
            aI.x = fmaf(p, vi.x, aI.x); aI.y = fmaf(p, vi.y, aI.y);
            aI.z = fmaf(p, vi.z, aI.z); aI.w = fmaf(p, vi.w, aI.w);
            aF.x = fmaf(p, vf.x, aF.x); aF.y = fmaf(p, vf.y, aF.y);
            aF.z = fmaf(p, vf.z, aF.z); aF.w = fmaf(p, vf.w, aF.w);
        }
#define RED(v) v += __shfl_xor(v, 16); v += __shfl_xor(v, 32)
        RED(aH.x); RED(aH.y); RED(aH.z); RED(aH.w);
        RED(aI.x); RED(aI.y); RED(aI.z); RED(aI.w);
        RED(aF.x); RED(aF.y); RED(aF.z); RED(aF.w);
#undef RED
        float4* o = (float4*)(out + (size_t)gid * 192);
        if (q == 0)      o[c4]      = aH;
        else if (q == 1) o[16 + c4] = aI;
        else if (q == 2) o[32 + c4] = aF;
    }
}

extern "C" void kernel_launch(void* const* d_in, const int* in_sizes, int n_in,
                              void* d_out, int out_size, void* d_ws, size_t ws_size,
                              hipStream_t stream) {
    const float* ht   = (const float*)d_in[0];
    const float* info = (const float*)d_in[1];
    const float* fut  = (const float*)d_in[2];
    const float* W1   = (const float*)d_in[3];
    const float* b1   = (const float*)d_in[4];
    const float* W2   = (const float*)d_in[5];
    const float* b2   = (const float*)d_in[6];
    const int*   seg  = (const int*)d_in[7];
    float*       out  = (float*)d_out;

    const int M = in_sizes[7];           // 262144 lanes
    const int blocks = M / 64;           // 4096 single-wave blocks

    lane_attn_kernel<<<blocks, 64, 0, stream>>>(ht, info, fut, W1, b1, W2, b2,
                                                seg, out);
}